// Round 2
// baseline (120.781 us; speedup 1.0000x reference)
//
#include <hip/hip_runtime.h>

// Problem constants (fixed by setup_inputs): B=2, C=32, H=128, W=256, maxdisp=12
#define BB 2
#define CC 32
#define HH 128
#define WW 256
#define MAXD 12
#define DD (2 * MAXD - 1)   // 23 shifts, shift = di - 11
#define NG 3                // disparity groups per (b,h) row
#define GSZ 8               // di per group (last group: 7 valid)
#define NC 328              // staged columns per block (covers all windows)
#define SC 36               // column stride in floats: 144 B, 16B-aligned
#define HW (HH * WW)

// LDS layout: smem[col*SC + c] = feat_r[b, c, h, col + COL0], zero outside [0,W).
// COL0 = 8g - 75. Window for pixel w, group g, j in [0,8]:
//   col_local = x0b + 64 + j, x0b = floor(w - disp) in [-64, 255]
//   -> col_local in [0, 327]  (fits NC=328 exactly)

__global__ __launch_bounds__(256, 3) void cost_volume_kernel(
    const float* __restrict__ feat_l,
    const float* __restrict__ feat_r,
    const float* __restrict__ disp,
    float* __restrict__ out)
{
    __shared__ __align__(16) float smem[NC * SC];   // 47232 B -> 3 blocks/CU

    const int t  = threadIdx.x;          // pixel w in compute phase
    const int g  = blockIdx.x >> 8;      // 0..2   (grid = NG * B*H, B*H = 256)
    const int bh = blockIdx.x & 255;
    const int b  = bh >> 7;              // H = 128
    const int h  = bh & 127;
    const int COL0 = 8 * g - 75;

    // ---- stage feat_r row, channel-interleaved, quad-channel b128 writes ----
    {
        const int colLane = t & 63;      // column within 64-chunk
        const int q0 = t >> 6;           // channel-quad 0..3 (then +4)
        #pragma unroll
        for (int cc = 0; cc < 6; ++cc) { // 6*64 = 384 >= NC
            const int col = cc * 64 + colLane;
            if (col < NC) {
                const int gcol = col + COL0;
                const bool inr = (gcol >= 0) && (gcol < WW);
                const int gc = min(max(gcol, 0), WW - 1);   // safe address
                #pragma unroll
                for (int qq = 0; qq < 2; ++qq) {
                    const int q = q0 + 4 * qq;              // 0..7
                    const size_t base =
                        ((size_t)(b * CC + 4 * q)) * HW + (size_t)h * WW + gc;
                    const float x0 = feat_r[base];
                    const float x1 = feat_r[base + HW];
                    const float x2 = feat_r[base + 2 * HW];
                    const float x3 = feat_r[base + 3 * HW];
                    float4 v;
                    v.x = inr ? x0 : 0.0f;
                    v.y = inr ? x1 : 0.0f;
                    v.z = inr ? x2 : 0.0f;
                    v.w = inr ? x3 : 0.0f;
                    // banks: (4*(col+q)) % 32 -> exactly 8 lanes per 4-bank
                    // group per instr = b128 minimum, no extra conflict
                    *(float4*)&smem[col * SC + 4 * q] = v;
                }
            }
        }
    }
    __syncthreads();

    // ---- per-pixel interpolation setup (shared across all di) ----
    const float d    = disp[(size_t)bh * WW + t];
    const float px   = (float)t - d;
    const float x0f  = floorf(px);
    const float w1   = px - x0f;         // right-neighbor weight
    const float w0   = 1.0f - w1;
    int x0b = (int)x0f;
    x0b = min(max(x0b, -64), WW - 1);    // no-op for disp in [0,64)
    const int lb = x0b + 64;             // local col of tap j=0

    float acc[GSZ];
    #pragma unroll
    for (int j = 0; j < GSZ; ++j) acc[j] = 0.0f;

    // ---- two channel halves (16 ch each) to bound register pressure ----
    #pragma unroll
    for (int half = 0; half < 2; ++half) {
        const int c0 = half * 16;

        float fl[16];
        #pragma unroll
        for (int k = 0; k < 16; ++k)
            fl[k] = feat_l[((size_t)(b * CC + c0 + k)) * HW + (size_t)h * WW + t];

        auto loadcol = [&](int j, float4* dst) {
            const float* cp = &smem[(lb + j) * SC + c0];
            #pragma unroll
            for (int k = 0; k < 4; ++k) dst[k] = *(const float4*)(cp + 4 * k);
        };
        auto dotstep = [&](const float4* Ca, const float4* Cb) -> float {
            float s0 = 0.0f, s1 = 0.0f;
            #pragma unroll
            for (int k = 0; k < 4; ++k) {
                s0 += fabsf(fmaf(w1, Cb[k].x, fmaf(w0, Ca[k].x, -fl[4*k+0])));
                s1 += fabsf(fmaf(w1, Cb[k].y, fmaf(w0, Ca[k].y, -fl[4*k+1])));
                s0 += fabsf(fmaf(w1, Cb[k].z, fmaf(w0, Ca[k].z, -fl[4*k+2])));
                s1 += fabsf(fmaf(w1, Cb[k].w, fmaf(w0, Ca[k].w, -fl[4*k+3])));
            }
            return s0 + s1;
        };

        float4 A[4], Bv[4];
        loadcol(0, A);
        #pragma unroll
        for (int jj = 0; jj < 4; ++jj) {       // ping-pong, no reg copies
            loadcol(2 * jj + 1, Bv);
            acc[2 * jj]     += dotstep(A, Bv);
            loadcol(2 * jj + 2, A);
            acc[2 * jj + 1] += dotstep(Bv, A);
        }
    }

    // ---- store this group's di planes (coalesced) ----
    #pragma unroll
    for (int j = 0; j < GSZ; ++j) {
        const int di = g * GSZ + j;
        if (di < DD)
            out[((size_t)(b * DD + di)) * HW + (size_t)h * WW + t] = acc[j];
    }
}

extern "C" void kernel_launch(void* const* d_in, const int* in_sizes, int n_in,
                              void* d_out, int out_size, void* d_ws, size_t ws_size,
                              hipStream_t stream)
{
    const float* feat_l = (const float*)d_in[0];
    const float* feat_r = (const float*)d_in[1];
    const float* disp   = (const float*)d_in[2];
    float* out = (float*)d_out;

    dim3 grid(NG * BB * HH);   // 768 blocks: (di-group, b, h)
    dim3 block(256);           // one thread per w
    cost_volume_kernel<<<grid, block, 0, stream>>>(feat_l, feat_r, disp, out);
}

// Round 3
// 77.423 us; speedup vs baseline: 1.5600x; 1.5600x over previous
//
#include <hip/hip_runtime.h>

// Problem constants: B=2, C=32, H=128, W=256, maxdisp=12 -> D=23, shift = di-11
#define BB 2
#define CC 32
#define HH 128
#define WW 256
#define DD 23
#define HW (HH * WW)

#define SEG 64            // pixels per block (W split 4 ways)
#define NSEG 4
#define NCOLS 151         // staged cols: [64s-75 .. 64s+75]  (64 + 87)
#define SC 36             // col stride in dwords (144 B, 16B-aligned, odd quad)
#define RED 23            // combine stride (23 coprime 32 -> conflict-free)

// LDS: smem[col*SC + c] = feat_r[b, c, h, col + COL0], zero outside [0,W).
// After compute it is reused as the cross-wave reduction buffer (3*64*23 floats).

__global__ __launch_bounds__(256, 4) void cost_volume_kernel(
    const float* __restrict__ feat_l,
    const float* __restrict__ feat_r,
    const float* __restrict__ disp,
    float* __restrict__ out)
{
    __shared__ __align__(16) float smem[NCOLS * SC];   // 21744 B -> LDS not limiter

    const int t  = threadIdx.x;
    const int q  = t >> 6;          // wave id = channel octet (c0 = 8q)
    const int px = t & 63;          // pixel within segment
    const int s  = blockIdx.x >> 8; // grid = NSEG*256; siblings same XCD (256%8==0)
    const int bh = blockIdx.x & 255;
    const int b  = bh >> 7;
    const int h  = bh & 127;
    const int w  = s * SEG + px;
    const int COL0 = s * SEG - 75;
    const int c0 = q * 8;

    // ---- early independent global loads (overlap staging latency) ----
    float fl[8];
    const size_t lbase = ((size_t)(b * CC + c0)) * HW + (size_t)h * WW + w;
    #pragma unroll
    for (int k = 0; k < 8; ++k) fl[k] = feat_l[lbase + (size_t)k * HW];
    const float d = disp[(size_t)bh * WW + w];

    // ---- stage feat_r window, channel-interleaved, b128 LDS writes ----
    #pragma unroll
    for (int cc = 0; cc < 3; ++cc) {
        const int col = cc * 64 + px;
        if (col < NCOLS) {
            const int  gcol = col + COL0;
            const bool inr  = (gcol >= 0) && (gcol < WW);
            const int  gc   = min(max(gcol, 0), WW - 1);   // safe address
            #pragma unroll
            for (int qq = 0; qq < 2; ++qq) {
                const int cq = (q + 4 * qq) * 4;           // channel quad base
                const size_t base = ((size_t)(b * CC + cq)) * HW + (size_t)h * WW + gc;
                const float x0 = feat_r[base];
                const float x1 = feat_r[base + HW];
                const float x2 = feat_r[base + 2 * HW];
                const float x3 = feat_r[base + 3 * HW];
                float4 v;
                v.x = inr ? x0 : 0.0f;
                v.y = inr ? x1 : 0.0f;
                v.z = inr ? x2 : 0.0f;
                v.w = inr ? x3 : 0.0f;
                *(float4*)&smem[col * SC + cq] = v;
            }
        }
    }
    __syncthreads();

    // ---- per-pixel interp setup (shared across all di) ----
    const float pxf = (float)w - d;
    const float x0f = floorf(pxf);
    const float w1  = pxf - x0f;          // right-neighbor weight
    const float w0  = 1.0f - w1;
    int lb = (int)x0f - COL0 - 11;        // local col of tap j=0
    lb = min(max(lb, 0), NCOLS - 24);     // no-op for disp in [0,64)

    // ---- 24-tap window, prefetch distance 2, 8 channels per thread ----
    float4 Ta[3], Tb[3];
    #define LOADTAP(idx, j) { \
        const float4* p_ = (const float4*)&smem[(lb + (j)) * SC + c0]; \
        Ta[idx] = p_[0]; Tb[idx] = p_[1]; }

    LOADTAP(0, 0)
    LOADTAP(1, 1)

    float acc[DD];
    #pragma unroll
    for (int di = 0; di < DD; ++di) {
        if (di + 2 < 24) LOADTAP((di + 2) % 3, di + 2)
        const float4 A0 = Ta[di % 3],       A1 = Tb[di % 3];
        const float4 B0 = Ta[(di + 1) % 3], B1 = Tb[(di + 1) % 3];
        float sA = 0.0f, sB = 0.0f;
        sA += fabsf(fmaf(w0, A0.x, fmaf(w1, B0.x, -fl[0])));
        sB += fabsf(fmaf(w0, A0.y, fmaf(w1, B0.y, -fl[1])));
        sA += fabsf(fmaf(w0, A0.z, fmaf(w1, B0.z, -fl[2])));
        sB += fabsf(fmaf(w0, A0.w, fmaf(w1, B0.w, -fl[3])));
        sA += fabsf(fmaf(w0, A1.x, fmaf(w1, B1.x, -fl[4])));
        sB += fabsf(fmaf(w0, A1.y, fmaf(w1, B1.y, -fl[5])));
        sA += fabsf(fmaf(w0, A1.z, fmaf(w1, B1.z, -fl[6])));
        sB += fabsf(fmaf(w0, A1.w, fmaf(w1, B1.w, -fl[7])));
        acc[di] = sA + sB;
    }
    #undef LOADTAP

    // ---- cross-wave channel combine (reuse smem; stride 23 = conflict-free) ----
    __syncthreads();                       // all tap reads done before overwrite
    if (q != 0) {
        float* r = &smem[(q - 1) * (64 * RED) + px * RED];
        #pragma unroll
        for (int di = 0; di < DD; ++di) r[di] = acc[di];
    }
    __syncthreads();
    if (q == 0) {
        const float* r0 = &smem[0 * (64 * RED) + px * RED];
        const float* r1 = &smem[1 * (64 * RED) + px * RED];
        const float* r2 = &smem[2 * (64 * RED) + px * RED];
        #pragma unroll
        for (int di = 0; di < DD; ++di) {
            const float v = acc[di] + r0[di] + r1[di] + r2[di];
            out[((size_t)(b * DD + di)) * HW + (size_t)h * WW + w] = v;
        }
    }
}

extern "C" void kernel_launch(void* const* d_in, const int* in_sizes, int n_in,
                              void* d_out, int out_size, void* d_ws, size_t ws_size,
                              hipStream_t stream)
{
    const float* feat_l = (const float*)d_in[0];
    const float* feat_r = (const float*)d_in[1];
    const float* disp   = (const float*)d_in[2];
    float* out = (float*)d_out;

    dim3 grid(NSEG * BB * HH);   // 1024 blocks: (wseg, b, h); 4 blocks/CU
    dim3 block(256);             // 4 waves: one channel-octet each
    cost_volume_kernel<<<grid, block, 0, stream>>>(feat_l, feat_r, disp, out);
}